// Round 10
// baseline (247.902 us; speedup 1.0000x reference)
//
#include <hip/hip_runtime.h>
#include <hip/hip_bf16.h>

constexpr int Bn = 64, Sn = 512, Hn = 768, Tn = 9;
constexpr int EMS = 12;                  // padded emission row stride (floats)
constexpr int CHUNKS = 32, CLEN = 16;    // CHUNKS*CLEN == Sn

typedef __attribute__((ext_vector_type(8))) short bf16x8;
typedef __attribute__((ext_vector_type(4))) float f32x4;

__device__ __forceinline__ short f2bf(float x) {
    __hip_bfloat16 h = __float2bfloat16(x);
    return *reinterpret_cast<short*>(&h);
}

__device__ __forceinline__ float lse9(const float* e) {
    float m01 = fmaxf(e[0], e[1]), m23 = fmaxf(e[2], e[3]);
    float m45 = fmaxf(e[4], e[5]), m67 = fmaxf(e[6], e[7]);
    float m = fmaxf(fmaxf(fmaxf(m01, m23), fmaxf(m45, m67)), e[8]);
    float s = 0.f;
#pragma unroll
    for (int k = 0; k < 9; ++k) s += __expf(e[k] - m);
    return m + __logf(s);
}

// ------------- K1 v3: register-direct A + LDS W-frag table MFMA -------------
// 512 blocks x 4 waves; wave-tile = 16 rows x 768. Lane (c16,hi) streams row
// c16's K-slices straight into registers (48 dwordx4 off one base, imm
// offsets, 2-deep A0/A1 double-buffer, static indexing). No barriers, no
// shuffles, no A-LDS. W: 24KB frag table, contiguous b128 reads.
__global__ __launch_bounds__(256) void emis_kernel(
        const float* __restrict__ hidden, const float* __restrict__ W,
        const float* __restrict__ bias, float* __restrict__ em) {
    __shared__ bf16x8 Wf[24 * 64];       // [mm][hi][c16], 24 KB
    const int tid = threadIdx.x, lane = tid & 63, wv = tid >> 6;

    for (int n = tid; n < 24 * 64; n += 256) {
        const int mm = n >> 6, hj = (n >> 4) & 3, cc = n & 15;
        bf16x8 bf;
#pragma unroll
        for (int e = 0; e < 8; ++e) {
            float w = (cc < Tn) ? W[(mm * 32 + hj * 8 + e) * Tn + cc] : 0.f;
            bf[e] = f2bf(w);
        }
        Wf[n] = bf;
    }
    __syncthreads();

    const int c16 = lane & 15, hi = lane >> 4;
    const int row0 = blockIdx.x * 64 + wv * 16;
    const float* base = hidden + (size_t)(row0 + c16) * Hn + hi * 8;

    f32x4 A0[4], A1[4];
    auto LD = [&](f32x4* A, int mmp) {
#pragma unroll
        for (int u = 0; u < 2; ++u) {
            A[2 * u]     = *reinterpret_cast<const f32x4*>(base + (2 * mmp + u) * 32);
            A[2 * u + 1] = *reinterpret_cast<const f32x4*>(base + (2 * mmp + u) * 32 + 4);
        }
    };
    auto CVT = [&](const f32x4& lo, const f32x4& hh) {
        bf16x8 af;
        af[0] = f2bf(lo[0]); af[1] = f2bf(lo[1]); af[2] = f2bf(lo[2]); af[3] = f2bf(lo[3]);
        af[4] = f2bf(hh[0]); af[5] = f2bf(hh[1]); af[6] = f2bf(hh[2]); af[7] = f2bf(hh[3]);
        return af;
    };

    f32x4 acc = {0.f, 0.f, 0.f, 0.f};
    LD(A0, 0);
#pragma unroll
    for (int mmp = 0; mmp < 12; mmp += 2) {
        LD(A1, mmp + 1);
#pragma unroll
        for (int u = 0; u < 2; ++u)
            acc = __builtin_amdgcn_mfma_f32_16x16x32_bf16(
                CVT(A0[2 * u], A0[2 * u + 1]),
                Wf[((2 * mmp + u) * 4 + hi) * 16 + c16], acc, 0, 0, 0);
        if (mmp + 2 < 12) LD(A0, mmp + 2);
#pragma unroll
        for (int u = 0; u < 2; ++u)
            acc = __builtin_amdgcn_mfma_f32_16x16x32_bf16(
                CVT(A1[2 * u], A1[2 * u + 1]),
                Wf[((2 * (mmp + 1) + u) * 4 + hi) * 16 + c16], acc, 0, 0, 0);
    }
    // D mapping: row = hi*4 + i, col = c16 (m89-verified; validated r6/r8/r9)
    if (c16 < Tn) {
        const float bc = bias[c16];
#pragma unroll
        for (int i = 0; i < 4; ++i)
            em[(size_t)(row0 + hi * 4 + i) * EMS + c16] = acc[i] + bc;
    }
}

// ---------------- K2: per-(batch,chunk) 9x9 log-matrix ----------------
__global__ __launch_bounds__(128) void chunk_kernel(
        const float* __restrict__ em, const float* __restrict__ trans,
        const int* __restrict__ labels, float* __restrict__ Mws) {
    const int b = blockIdx.x / CHUNKS;
    const int c = blockIdx.x % CHUNKS;
    const int tid = threadIdx.x;
    const bool act = tid < 81;
    const int i = tid / 9, j = tid % 9;
    __shared__ float Mbuf[2][9][12];
    __shared__ float emch[CLEN][EMS];
    __shared__ int   labch[CLEN];
    const int s0 = c * CLEN;
    const float* emb = em + ((size_t)b * Sn + s0) * EMS;
    for (int idx = tid; idx < CLEN * EMS; idx += 128)
        (&emch[0][0])[idx] = emb[idx];
    if (tid < CLEN) labch[tid] = labels[b * Sn + s0 + tid];
    float tc[9], row[9];
    float nv = (i == j) ? 0.f : -1e30f;
    if (act) {
#pragma unroll
        for (int k = 0; k < 9; ++k) tc[k] = trans[k * 9 + j];
#pragma unroll
        for (int k = 0; k < 9; ++k) row[k] = (k == i) ? 0.f : -1e30f;
    }
    __syncthreads();
    const int sbeg = (c == 0) ? 1 : 0;
    for (int sl = sbeg; sl < CLEN; ++sl) {
        if (act) {
            float e[9];
#pragma unroll
            for (int k = 0; k < 9; ++k) e[k] = row[k] + tc[k];
            float cand = lse9(e) + emch[sl][j];
            if (labch[sl] > -1) nv = cand;
            Mbuf[sl & 1][i][j] = nv;
        }
        __syncthreads();
        if (act) {
#pragma unroll
            for (int k = 0; k < 9; ++k) row[k] = Mbuf[sl & 1][i][k];
        }
    }
    if (act) Mws[(size_t)(b * CHUNKS + c) * 81 + tid] = nv;
}

// ---------------- K3: fold chunks + numerator + output ----------------
__global__ __launch_bounds__(128) void final_kernel(
        const float* __restrict__ em, const float* __restrict__ Mws,
        const float* __restrict__ start, const float* __restrict__ endt,
        const float* __restrict__ trans, const int* __restrict__ labels,
        float* __restrict__ out) {
    const int b = blockIdx.x, tid = threadIdx.x;
    __shared__ float Ml[CHUNKS][9][12];
    __shared__ float red[128];
    for (int idx = tid; idx < CHUNKS * 81; idx += 128) {
        int c = idx / 81, r = idx % 81;
        Ml[c][r / 9][r % 9] = Mws[(size_t)(b * CHUNKS + c) * 81 + r];
    }
    const int* lb = labels + b * Sn;
    float np = 0.f;
    for (int s = tid; s < Sn; s += 128) {
        if (s >= 1) {
            int l = lb[s];
            if (l > -1) {
                int tp = lb[s - 1]; tp = tp > -1 ? tp : 0;
                np += trans[tp * 9 + l] + em[((size_t)b * Sn + s) * EMS + l];
            }
        }
    }
    red[tid] = np;
    __syncthreads();
    for (int off = 64; off > 0; off >>= 1) {
        if (tid < off) red[tid] += red[tid + off];
        __syncthreads();
    }
    if (tid < 9) {
        const int j = tid;
        float alpha[9];
#pragma unroll
        for (int k = 0; k < 9; ++k)
            alpha[k] = start[k] + em[(size_t)b * Sn * EMS + k];
        for (int c = 0; c < CHUNKS; ++c) {
            float e[9];
#pragma unroll
            for (int k = 0; k < 9; ++k) e[k] = alpha[k] + Ml[c][k][j];
            float nv = lse9(e);
#pragma unroll
            for (int k = 0; k < 9; ++k) alpha[k] = __shfl(nv, k, 64);
        }
        if (j == 0) {
            float e[9];
#pragma unroll
            for (int k = 0; k < 9; ++k) e[k] = alpha[k] + endt[k];
            float den = lse9(e);
            int t0 = lb[0] > -1 ? lb[0] : 0;
            float num = red[0] + start[t0] + em[(size_t)b * Sn * EMS + t0];
            int lt = lb[Sn - 1] > -1 ? lb[Sn - 1] : 0;
            num += endt[lt];
            atomicAdd(out, (den - num) * (1.0f / Bn));
        }
    }
}

extern "C" void kernel_launch(void* const* d_in, const int* in_sizes, int n_in,
                              void* d_out, int out_size, void* d_ws, size_t ws_size,
                              hipStream_t stream) {
    const float* hidden = (const float*)d_in[0];
    const float* W      = (const float*)d_in[1];
    const float* bias   = (const float*)d_in[2];
    const float* start  = (const float*)d_in[3];
    const float* endt   = (const float*)d_in[4];
    const float* trans  = (const float*)d_in[5];
    const int*   labels = (const int*)d_in[6];
    float* out = (float*)d_out;

    float* em   = (float*)d_ws;                      // 393216 floats
    float* Mws  = em + (size_t)Bn * Sn * EMS;        // 165888 floats
    float* dum1 = Mws + (size_t)Bn * CHUNKS * 81;    // diagnostic dummies
    float* dum2 = dum1 + (size_t)Bn * Sn * EMS;

    hipMemsetAsync(d_out, 0, sizeof(float), stream);
    // DIAGNOSTIC: emis launched 3x (2 into dummy buffers) to expose its true
    // duration in dur_us delta / top-5. Remove dummies once measured.
    emis_kernel<<<512, 256, 0, stream>>>(hidden, W, bias, em);
    emis_kernel<<<512, 256, 0, stream>>>(hidden, W, bias, dum1);
    emis_kernel<<<512, 256, 0, stream>>>(hidden, W, bias, dum2);
    chunk_kernel<<<Bn * CHUNKS, 128, 0, stream>>>(em, trans, labels, Mws);
    final_kernel<<<Bn, 128, 0, stream>>>(em, Mws, start, endt, trans, labels, out);
}